// Round 4
// baseline (1199.209 us; speedup 1.0000x reference)
//
#include <hip/hip_runtime.h>
#include <cstdint>
#include <cstddef>

#define NB 8
#define NPTS 8192
#define S_TOT 512
#define NSAMP 64
#define DFEAT 64
#define INCH 67
#define SLOTS 68
#define CCAP (SLOTS * 64)   // 4352 compacted slots per (b,grp)

// exact (numpy-matching) squared distance: (a-b) per component, square, sum as (x+y)+z
__device__ __forceinline__ float d2_exact(float ax, float ay, float az,
                                          float bx, float by, float bz) {
    float dx = __fsub_rn(ax, bx);
    float dy = __fsub_rn(ay, by);
    float dz = __fsub_rn(az, bz);
    return __fadd_rn(__fadd_rn(__fmul_rn(dx, dx), __fmul_rn(dy, dy)), __fmul_rn(dz, dz));
}

// u64 max combine with a DPP-shifted copy (VALU pipe — no DS latency).
// bound_ctrl=false + old=self => lanes with invalid source keep self (max-safe).
template <int CTRL>
__device__ __forceinline__ unsigned long long dpp_max_u64(unsigned long long k) {
    int lo = (int)(unsigned)(k & 0xffffffffull);
    int hi = (int)(unsigned)(k >> 32);
    int slo = __builtin_amdgcn_update_dpp(lo, lo, CTRL, 0xf, 0xf, false);
    int shi = __builtin_amdgcn_update_dpp(hi, hi, CTRL, 0xf, 0xf, false);
    unsigned long long o = ((unsigned long long)(unsigned)shi << 32) | (unsigned)slo;
    return (o > k) ? o : k;
}

// ---------------------------------------------------------------------------
// FPS stage 1: compact + SORT-PRESERVING rep insertion.
// attention is 0/1, so masked-out points are exactly (+/-0,+/-0,+/-0) with
// bit-identical min_d2 trajectories -> collapse to ONE representative at the
// min masked index rm. All indices < rm are kept, so the rep's sorted slot is
// exactly rm; kept points with idx > rm shift +1. Resulting slot order ==
// original index order (makes slot-based tie-breaks == numpy first-occurrence).
// ---------------------------------------------------------------------------
__global__ __launch_bounds__(1024) void fps_compact(
    const float* __restrict__ xyz, const float* __restrict__ attn,
    float4* __restrict__ cxyz,   // [16][CCAP]
    int* __restrict__ hdr)       // [16][2] = {M, rm or -1}
{
    int blk = blockIdx.x;
    int b = blk >> 1, grp = blk & 1;
    const float* xb = xyz + (size_t)b * 3 * NPTS;
    const float* ab = attn + (size_t)b * NPTS;
    float4* c4 = cxyz + (size_t)blk * CCAP;

    int tid = threadIdx.x, lane = tid & 63, wid = tid >> 6;
    int n0 = tid * 8;

    __shared__ int s_repmin;
    __shared__ int s_ws[16];
    if (tid == 0) s_repmin = NPTS;
    __syncthreads();

    float av[8];
    *(float4*)&av[0] = *(const float4*)(ab + n0);
    *(float4*)&av[4] = *(const float4*)(ab + n0 + 4);
    int cnt = 0, mymin = NPTS;
    bool keep[8];
#pragma unroll
    for (int j = 0; j < 8; j++) {
        keep[j] = grp ? (av[j] == 0.0f) : (av[j] != 0.0f);
        cnt += keep[j] ? 1 : 0;
        if (!keep[j] && n0 + j < mymin) mymin = n0 + j;
    }
    if (mymin < NPTS) atomicMin(&s_repmin, mymin);

    int incl = cnt;
#pragma unroll
    for (int off = 1; off <= 32; off <<= 1) {
        int t = __shfl_up(incl, off);
        if (lane >= off) incl += t;
    }
    if (lane == 63) s_ws[wid] = incl;
    __syncthreads();
    int woff = 0, tot = 0;
#pragma unroll
    for (int w = 0; w < 16; w++) { if (w < wid) woff += s_ws[w]; tot += s_ws[w]; }
    int pos = woff + incl - cnt;
    int rm = s_repmin;
    int rm_eff = (rm < NPTS) ? rm : 0x7fffffff;

    float xv[8], yv[8], zv[8];
    *(float4*)&xv[0] = *(const float4*)(xb + n0);
    *(float4*)&xv[4] = *(const float4*)(xb + n0 + 4);
    *(float4*)&yv[0] = *(const float4*)(xb + NPTS + n0);
    *(float4*)&yv[4] = *(const float4*)(xb + NPTS + n0 + 4);
    *(float4*)&zv[0] = *(const float4*)(xb + 2 * NPTS + n0);
    *(float4*)&zv[4] = *(const float4*)(xb + 2 * NPTS + n0 + 4);
#pragma unroll
    for (int j = 0; j < 8; j++) {
        if (keep[j]) {
            int fin = pos + ((n0 + j > rm_eff) ? 1 : 0);   // kept f==1 -> coords = raw x (1.0*x == x)
            c4[fin] = make_float4(xv[j], yv[j], zv[j], 0.0f);
            pos++;
        }
    }
    if (tid == 0) {
        int M = tot;
        if (rm < NPTS) {   // rep: signed zeros exactly like 0.0f*x
            c4[rm] = make_float4(__fmul_rn(0.0f, xb[rm]),
                                 __fmul_rn(0.0f, xb[NPTS + rm]),
                                 __fmul_rn(0.0f, xb[2 * NPTS + rm]), 0.0f);
            M++;
        }
        hdr[blk * 2] = M;
        hdr[blk * 2 + 1] = (rm < NPTS) ? rm : -1;
    }
}

// ---------------------------------------------------------------------------
// FPS stage 2: ONE WAVE per (b,grp). 68 slots/lane in registers (~300 VGPR,
// 1 wave/SIMD => no spill under the 450 line). Serial chain per iteration has
// ZERO barriers and ONE LDS access: update (ALU, pipelined) -> pack
// (md_bits<<32)|~slot -> 6-step DPP u64 max (VALU) -> readlane -> ds_read_b128
// winner coords. Tie-break: per-lane strict '>' over ascending slots + ~slot
// in the key == numpy argmax first-occurrence (slot order == index order).
// ---------------------------------------------------------------------------
__global__ __launch_bounds__(64, 1) void fps_iter(
    const float* __restrict__ attn,
    const float4* __restrict__ cxyz,
    const int* __restrict__ hdr,
    float* __restrict__ out0, float* __restrict__ out2)
{
    int blk = blockIdx.x;
    int b = blk >> 1, grp = blk & 1;
    int K = grp ? 384 : 128;
    int soff = grp ? 128 : 0;
    int M = hdr[blk * 2];
    int repslot = hdr[blk * 2 + 1];   // == rm, or -1
    if (M > CCAP) return;             // fps_fallback covers this block
    int lane = threadIdx.x;

    const float4* cb = cxyz + (size_t)blk * CCAP;
    __shared__ float4 sc[CCAP];

    float px[SLOTS], py[SLOTS], pz[SLOTS], md[SLOTS];
#pragma unroll
    for (int i = 0; i < SLOTS; i++) {
        int sl = i * 64 + lane;
        bool v = sl < M;
        float4 c = v ? cb[sl] : make_float4(0.f, 0.f, 0.f, 0.f);
        px[i] = c.x; py[i] = c.y; pz[i] = c.z;
        sc[sl] = c;
        md[i] = v ? 1e10f : -1.0f;    // invalid: never wins (d2 >= 0)
    }
    // slot 0 <-> original index 0 always (kept below rm sit at pos==idx; if
    // rm==0 the rep sits at slot 0). Start point = index 0 per reference.
    float4 c0 = cb[0];
    float lx = c0.x, ly = c0.y, lz = c0.z;
    float a_last = attn[(size_t)b * NPTS];
    float kept_a = grp ? 0.0f : 1.0f;
    float rep_a  = grp ? 1.0f : 0.0f;

    for (int k = 0; k < K; k++) {
        if (lane == 0) {
            int sg = soff + k;
            out0[(size_t)b * 3 * S_TOT + sg] = lx;
            out0[(size_t)b * 3 * S_TOT + S_TOT + sg] = ly;
            out0[(size_t)b * 3 * S_TOT + 2 * S_TOT + sg] = lz;
            out2[(size_t)b * S_TOT + sg] = a_last;
        }
        if (k == K - 1) break;

        float bv = -1.0f; int bi = 0;
        // 4 x 17 nests: 17-trip bodies provably fully unroll (R3 evidence)
#pragma unroll
        for (int c = 0; c < 4; c++) {
#pragma unroll
            for (int i2 = 0; i2 < 17; i2++) {
                const int i = c * 17 + i2;
                float d2 = d2_exact(px[i], py[i], pz[i], lx, ly, lz);
                md[i] = fminf(md[i], d2);
                bool w = md[i] > bv;          // strict >: first occurrence
                bi = w ? i : bi;
                bv = fmaxf(bv, md[i]);
            }
        }
        int bslot = (bi << 6) | lane;
        unsigned long long key = (bv >= 0.0f)
            ? (((unsigned long long)__float_as_uint(bv) << 32) | (unsigned)(~bslot))
            : 0ull;
        key = dpp_max_u64<0x111>(key);   // row_shr:1
        key = dpp_max_u64<0x112>(key);   // row_shr:2
        key = dpp_max_u64<0x114>(key);   // row_shr:4
        key = dpp_max_u64<0x118>(key);   // row_shr:8
        key = dpp_max_u64<0x142>(key);   // row_bcast:15
        key = dpp_max_u64<0x143>(key);   // row_bcast:31  -> lane 63 = global max
        unsigned lo = (unsigned)__builtin_amdgcn_readlane((int)(unsigned)(key & 0xffffffffull), 63);
        int wslot = (int)(~lo);
        float4 wc = sc[wslot];            // single ds_read_b128, broadcast
        lx = wc.x; ly = wc.y; lz = wc.z;
        a_last = (wslot == repslot) ? rep_a : kept_a;
    }
}

// ---------------------------------------------------------------------------
// Fallback FPS over all 8192 points (R2 structure). Runs only when hdr says a
// block overflowed CCAP (|kept-4096| > 255 ~ 5.7 sigma) or ws too small.
// ---------------------------------------------------------------------------
__global__ __launch_bounds__(1024, 1) void fps_kernel(
    const float* __restrict__ xyz, const float* __restrict__ attn,
    const int* __restrict__ hdr,
    float* __restrict__ out0, float* __restrict__ out2)
{
    int blk = blockIdx.x;
    if (hdr != nullptr && hdr[blk * 2] <= CCAP) return;
    int b = blk >> 1, grp = blk & 1;
    int K = grp ? 384 : 128;
    int soff = grp ? 128 : 0;
    int tid = threadIdx.x, lane = tid & 63, wid = tid >> 6;
    const float* xb = xyz + (size_t)b * 3 * NPTS;
    const float* ab = attn + (size_t)b * NPTS;

    float px[8], py[8], pz[8], md[8];
#pragma unroll
    for (int i = 0; i < 8; i++) {
        int n = tid + i * 1024;
        float a = ab[n];
        float f = grp ? __fsub_rn(1.0f, a) : a;
        px[i] = __fmul_rn(f, xb[n]);
        py[i] = __fmul_rn(f, xb[NPTS + n]);
        pz[i] = __fmul_rn(f, xb[2 * NPTS + n]);
        md[i] = 1e10f;
    }
    __shared__ unsigned long long s_red[2][16];
    float a_last = ab[0];
    float f0 = grp ? __fsub_rn(1.0f, a_last) : a_last;
    float lx = __fmul_rn(f0, xb[0]);
    float ly = __fmul_rn(f0, xb[NPTS]);
    float lz = __fmul_rn(f0, xb[2 * NPTS]);

    for (int k = 0; k < K; k++) {
        if (tid == 0) {
            int sg = soff + k;
            out0[(size_t)b * 3 * S_TOT + sg] = lx;
            out0[(size_t)b * 3 * S_TOT + S_TOT + sg] = ly;
            out0[(size_t)b * 3 * S_TOT + 2 * S_TOT + sg] = lz;
            out2[(size_t)b * S_TOT + sg] = a_last;
        }
        if (k == K - 1) break;
        float bv = -1.0f; int bi = 0;
#pragma unroll
        for (int i = 0; i < 8; i++) {
            float d2 = d2_exact(px[i], py[i], pz[i], lx, ly, lz);
            md[i] = fminf(md[i], d2);
            if (md[i] > bv) { bv = md[i]; bi = tid + i * 1024; }
        }
        unsigned long long best =
            ((unsigned long long)__float_as_uint(bv) << 32) | (unsigned)(~bi);
#pragma unroll
        for (int off = 32; off >= 1; off >>= 1) {
            unsigned long long o = __shfl_down(best, off);
            best = (o > best) ? o : best;
        }
        if (lane == 0) s_red[k & 1][wid] = best;
        __syncthreads();
        unsigned long long r = (lane < 16) ? s_red[k & 1][lane] : 0ull;
#pragma unroll
        for (int off = 8; off >= 1; off >>= 1) {
            unsigned long long o = __shfl_down(r, off);
            r = (o > r) ? o : r;
        }
        r = __shfl(r, 0);
        int n = (int)(~(unsigned)r);
        a_last = ab[n];
        float fl = grp ? __fsub_rn(1.0f, a_last) : a_last;
        lx = __fmul_rn(fl, xb[n]);
        ly = __fmul_rn(fl, xb[NPTS + n]);
        lz = __fmul_rn(fl, xb[2 * NPTS + n]);
    }
}

// ---------------------------------------------------------------------------
// points [B,64,N] -> ptsT [B,N,64], tiled 64x64 via LDS
// ---------------------------------------------------------------------------
__global__ void transpose_pts(const float* __restrict__ pts, float* __restrict__ ptsT) {
    __shared__ float t[64][65];
    int b = blockIdx.y;
    int n0 = blockIdx.x * 64;
    int tx = threadIdx.x, ty = threadIdx.y;
    for (int c = ty; c < 64; c += 4)
        t[c][tx] = pts[((size_t)b * DFEAT + c) * NPTS + n0 + tx];
    __syncthreads();
    for (int r = ty; r < 64; r += 4)
        ptsT[((size_t)b * NPTS + n0 + r) * DFEAT + tx] = t[tx][r];
}

// w0 [64][67] -> w0T [67][64]; w1 [64][64] -> w1T [64][64]
__global__ void transpose_w(const float* __restrict__ w0, const float* __restrict__ w1,
                            float* __restrict__ w0T, float* __restrict__ w1T) {
    int t = blockIdx.x * 256 + threadIdx.x;
    if (t < INCH * 64) { int o = t & 63, c = t >> 6; w0T[c * 64 + o] = w0[o * INCH + c]; }
    if (t < 64 * 64)   { int o = t & 63, c = t >> 6; w1T[c * 64 + o] = w1[o * 64 + c]; }
}

// ---------------------------------------------------------------------------
// Ball query + 3-layer MLP + max over 64 samples. One wave per query.
// h1 is staged through LDS so layer 2's c-loop needs NO full unroll ->
// h1[c] is a ds_read, never scratch (R3's 67 MB FETCH == h1 scratch reads).
// Peak live regs ~75 (h2[64] + temps).
// ---------------------------------------------------------------------------
__global__ __launch_bounds__(64, 1) void ball_mlp(
    const float* __restrict__ xyz,
    const float* __restrict__ pts,
    const float* __restrict__ ptsT,
    int use_ptsT,
    const float* __restrict__ w0T, const float* __restrict__ w1T, int use_wT,
    const float* __restrict__ w0, const float* __restrict__ b0,
    const float* __restrict__ w1, const float* __restrict__ b1,
    const float* __restrict__ w2, const float* __restrict__ b2,
    const float* __restrict__ out0,
    float* __restrict__ out1)
{
    const float R2 = (float)(0.4 * 0.4);   // 0x3E23D70A — NOT 0.4f*0.4f
    int q = blockIdx.x;
    int b = q >> 9;
    int sg = q & 511;
    int lane = threadIdx.x;

    const float* xb = xyz + (size_t)b * 3 * NPTS;
    float qx = out0[(size_t)b * 3 * S_TOT + sg];
    float qy = out0[(size_t)b * 3 * S_TOT + S_TOT + sg];
    float qz = out0[(size_t)b * 3 * S_TOT + 2 * S_TOT + sg];

    __shared__ int s_idx[NSAMP];
    __shared__ float s_h1[64 * 64];   // [c][lane]
    int cnt = 0;
#pragma unroll 4
    for (int base = 0; base < NPTS; base += 64) {   // no early exit: loads stay independent
        int n = base + lane;
        float d2 = d2_exact(qx, qy, qz, xb[n], xb[NPTS + n], xb[2 * NPTS + n]);
        bool flag = d2 < R2;
        unsigned long long m = __ballot(flag);
        int pos = cnt + (int)__popcll(m & ((1ull << lane) - 1ull));
        if (flag && pos < NSAMP) s_idx[pos] = n;
        cnt += (int)__popcll(m);
    }
    __syncthreads();
    if (cnt > NSAMP) cnt = NSAMP;

    int nb = (lane < cnt) ? s_idx[lane] : -1;
    float nx_ = 0.f, ny_ = 0.f, nz_ = 0.f;
    if (nb >= 0) { nx_ = xb[nb]; ny_ = xb[NPTS + nb]; nz_ = xb[2 * NPTS + nb]; }
    float fx = nx_ - qx, fy = ny_ - qy, fz = nz_ - qz;   // pad: -new_xyz (ref semantics)
    int row = (nb < 0) ? (NPTS - 1) : nb;                // torch -1 wraps to last point

    // ---- layer 1: 67 -> 64 (h1[o] accumulators, inner o-loop unrolled) ----
    float h1[64];
    if (use_wT) {
#pragma unroll
        for (int o = 0; o < 64; o++) {
            float a = __builtin_fmaf(w0T[o], fx, b0[o]);
            a = __builtin_fmaf(w0T[64 + o], fy, a);
            h1[o] = __builtin_fmaf(w0T[128 + o], fz, a);
        }
        if (use_ptsT) {
            const float* prow = ptsT + ((size_t)b * NPTS + row) * DFEAT;
#pragma unroll 1
            for (int c = 0; c < 64; c += 4) {
                float4 f4 = *(const float4*)(prow + c);
                const float* wr = w0T + (3 + c) * 64;
#pragma unroll
                for (int o = 0; o < 64; o++) {
                    float a = __builtin_fmaf(wr[o], f4.x, h1[o]);
                    a = __builtin_fmaf(wr[64 + o], f4.y, a);
                    a = __builtin_fmaf(wr[128 + o], f4.z, a);
                    h1[o] = __builtin_fmaf(wr[192 + o], f4.w, a);
                }
            }
        } else {
            const float* pb = pts + (size_t)b * DFEAT * NPTS + row;
#pragma unroll 1
            for (int c = 0; c < 64; c++) {
                float f = pb[(size_t)c * NPTS];
                const float* wr = w0T + (3 + c) * 64;
#pragma unroll
                for (int o = 0; o < 64; o++)
                    h1[o] = __builtin_fmaf(wr[o], f, h1[o]);
            }
        }
    } else {
#pragma unroll
        for (int o = 0; o < 64; o++) {
            float a = __builtin_fmaf(w0[o * INCH + 0], fx, b0[o]);
            a = __builtin_fmaf(w0[o * INCH + 1], fy, a);
            h1[o] = __builtin_fmaf(w0[o * INCH + 2], fz, a);
        }
        const float* pb = pts + (size_t)b * DFEAT * NPTS + row;
#pragma unroll 1
        for (int c = 0; c < 64; c++) {
            float f = use_ptsT ? ptsT[((size_t)b * NPTS + row) * DFEAT + c]
                               : pb[(size_t)c * NPTS];
#pragma unroll
            for (int o = 0; o < 64; o++)
                h1[o] = __builtin_fmaf(w0[o * INCH + 3 + c], f, h1[o]);
        }
    }
    // relu + stage through LDS (frees the h1 registers for layer 2)
#pragma unroll
    for (int o = 0; o < 64; o++) s_h1[o * 64 + lane] = fmaxf(h1[o], 0.0f);
    __syncthreads();   // single-wave block: cheap; orders LDS for the reads below

    // ---- layer 2: 64 -> 64 (h1 from LDS: runtime c is fine, no scratch) ----
    float h2[64];
#pragma unroll
    for (int o = 0; o < 64; o++) h2[o] = b1[o];
#pragma unroll 1
    for (int c = 0; c < 64; c++) {
        float hc = s_h1[c * 64 + lane];
        if (use_wT) {
            const float* wr = w1T + c * 64;
#pragma unroll
            for (int o = 0; o < 64; o++)
                h2[o] = __builtin_fmaf(wr[o], hc, h2[o]);
        } else {
#pragma unroll
            for (int o = 0; o < 64; o++)
                h2[o] = __builtin_fmaf(w1[o * 64 + c], hc, h2[o]);
        }
    }
#pragma unroll
    for (int o = 0; o < 64; o++) h2[o] = fmaxf(h2[o], 0.0f);

    // ---- layer 3: 64 -> 128, relu, lane-max (shuffle chains overlap VALU) ----
#pragma unroll 2
    for (int o = 0; o < 128; o++) {
        const float* wr = w2 + o * 64;
        float acc = b2[o];
#pragma unroll
        for (int c = 0; c < 64; c++) acc = __builtin_fmaf(wr[c], h2[c], acc);
        acc = fmaxf(acc, 0.0f);   // relu(max) == max(relu): monotone
#pragma unroll
        for (int off = 32; off >= 1; off >>= 1)
            acc = fmaxf(acc, __shfl_down(acc, off));
        if (lane == 0) out1[((size_t)(b * 128 + o)) * S_TOT + sg] = acc;
    }
}

extern "C" void kernel_launch(void* const* d_in, const int* in_sizes, int n_in,
                              void* d_out, int out_size, void* d_ws, size_t ws_size,
                              hipStream_t stream) {
    const float* xyz  = (const float*)d_in[0];
    const float* pts  = (const float*)d_in[1];
    const float* attn = (const float*)d_in[2];
    const float* w0 = (const float*)d_in[3];
    const float* b0 = (const float*)d_in[4];
    const float* w1 = (const float*)d_in[5];
    const float* b1 = (const float*)d_in[6];
    const float* w2 = (const float*)d_in[7];
    const float* b2 = (const float*)d_in[8];

    float* out0 = (float*)d_out;                    // [B,3,S]   = 12288
    float* out1 = out0 + (size_t)NB * 3 * S_TOT;    // [B,128,S] = 524288
    float* out2 = out1 + (size_t)NB * 128 * S_TOT;  // [B,1,S]   = 4096

    // ws layout (floats): w0T(4288) w1T(4096) pad->8448 | ptsT 4194304 |
    //   cxyz 16*CCAP*4 | hdr 32 ints
    float*  w0T  = (float*)d_ws;
    float*  w1T  = w0T + INCH * 64;
    float*  ptsT = w0T + 8448;
    float4* cxyz = (float4*)(ptsT + (size_t)NB * NPTS * DFEAT);
    int*    hdr  = (int*)(cxyz + (size_t)16 * CCAP);

    const size_t wT_f   = 8448;
    const size_t ptsT_f = (size_t)NB * NPTS * DFEAT;
    const size_t full_f = wT_f + ptsT_f + (size_t)16 * CCAP * 4 + 32;
    int use_wT   = (ws_size >= wT_f * 4) ? 1 : 0;
    int use_ptsT = (ws_size >= (wT_f + ptsT_f) * 4) ? 1 : 0;
    int use_fps2 = (ws_size >= full_f * 4) ? 1 : 0;

    if (use_fps2) {
        fps_compact<<<16, 1024, 0, stream>>>(xyz, attn, cxyz, hdr);
        fps_iter<<<16, 64, 0, stream>>>(attn, cxyz, hdr, out0, out2);
        fps_kernel<<<16, 1024, 0, stream>>>(xyz, attn, hdr, out0, out2);  // gated fallback
    } else {
        fps_kernel<<<16, 1024, 0, stream>>>(xyz, attn, nullptr, out0, out2);
    }
    if (use_wT)
        transpose_w<<<(INCH * 64 + 255) / 256, 256, 0, stream>>>(w0, w1, w0T, w1T);
    if (use_ptsT)
        transpose_pts<<<dim3(NPTS / 64, NB), dim3(64, 4), 0, stream>>>(pts, ptsT);
    ball_mlp<<<NB * S_TOT, 64, 0, stream>>>(xyz, pts, ptsT, use_ptsT,
                                            w0T, w1T, use_wT,
                                            w0, b0, w1, b1, w2, b2, out0, out1);
}

// Round 5
// 1084.399 us; speedup vs baseline: 1.1059x; 1.1059x over previous
//
#include <hip/hip_runtime.h>
#include <cstdint>
#include <cstddef>

#define NB 8
#define NPTS 8192
#define S_TOT 512
#define NSAMP 64
#define DFEAT 64
#define INCH 67
#define SLOTS 17
#define CCAP (SLOTS * 256)   // 4352 compacted slots per (b,grp)

// exact (numpy-matching) squared distance: (a-b) per component, square, sum as (x+y)+z
__device__ __forceinline__ float d2_exact(float ax, float ay, float az,
                                          float bx, float by, float bz) {
    float dx = __fsub_rn(ax, bx);
    float dy = __fsub_rn(ay, by);
    float dz = __fsub_rn(az, bz);
    return __fadd_rn(__fadd_rn(__fmul_rn(dx, dx), __fmul_rn(dy, dy)), __fmul_rn(dz, dz));
}

// u64 max combine with a DPP-shifted copy (VALU pipe — no DS latency).
// old=self + bound_ctrl=false => lanes w/o valid source keep self (max-safe).
// Chain row_shr 1,2,4,8 + row_bcast15 + row_bcast31 => lane 63 = wave max
// (hardware-verified in R4: passed with absmax 0.0).
template <int CTRL>
__device__ __forceinline__ unsigned long long dpp_max_u64(unsigned long long k) {
    int lo = (int)(unsigned)(k & 0xffffffffull);
    int hi = (int)(unsigned)(k >> 32);
    int slo = __builtin_amdgcn_update_dpp(lo, lo, CTRL, 0xf, 0xf, false);
    int shi = __builtin_amdgcn_update_dpp(hi, hi, CTRL, 0xf, 0xf, false);
    unsigned long long o = ((unsigned long long)(unsigned)shi << 32) | (unsigned)slo;
    return (o > k) ? o : k;
}

template <int CTRL>
__device__ __forceinline__ float dpp_max_f32(float v) {
    int s = __builtin_amdgcn_update_dpp(__float_as_int(v), __float_as_int(v),
                                        CTRL, 0xf, 0xf, false);
    return fmaxf(v, __int_as_float(s));
}

// ---------------------------------------------------------------------------
// FPS stage 1: compact + SORT-PRESERVING rep insertion.
// attention is 0/1 -> masked-out points are exactly (+/-0,+/-0,+/-0) with
// bit-identical min_d2 trajectories; collapse to ONE representative at the min
// masked index rm. Indices < rm are all kept, so the rep's sorted slot is rm;
// kept idx > rm shift +1. Slot order == original index order.
// ---------------------------------------------------------------------------
__global__ __launch_bounds__(1024) void fps_compact(
    const float* __restrict__ xyz, const float* __restrict__ attn,
    float4* __restrict__ cxyz,   // [16][CCAP]
    int* __restrict__ hdr)       // [16][2] = {M, rm or -1}
{
    int blk = blockIdx.x;
    int b = blk >> 1, grp = blk & 1;
    const float* xb = xyz + (size_t)b * 3 * NPTS;
    const float* ab = attn + (size_t)b * NPTS;
    float4* c4 = cxyz + (size_t)blk * CCAP;

    int tid = threadIdx.x, lane = tid & 63, wid = tid >> 6;
    int n0 = tid * 8;

    __shared__ int s_repmin;
    __shared__ int s_ws[16];
    if (tid == 0) s_repmin = NPTS;
    __syncthreads();

    float av[8];
    *(float4*)&av[0] = *(const float4*)(ab + n0);
    *(float4*)&av[4] = *(const float4*)(ab + n0 + 4);
    int cnt = 0, mymin = NPTS;
    bool keep[8];
#pragma unroll
    for (int j = 0; j < 8; j++) {
        keep[j] = grp ? (av[j] == 0.0f) : (av[j] != 0.0f);
        cnt += keep[j] ? 1 : 0;
        if (!keep[j] && n0 + j < mymin) mymin = n0 + j;
    }
    if (mymin < NPTS) atomicMin(&s_repmin, mymin);

    int incl = cnt;
#pragma unroll
    for (int off = 1; off <= 32; off <<= 1) {
        int t = __shfl_up(incl, off);
        if (lane >= off) incl += t;
    }
    if (lane == 63) s_ws[wid] = incl;
    __syncthreads();
    int woff = 0, tot = 0;
#pragma unroll
    for (int w = 0; w < 16; w++) { if (w < wid) woff += s_ws[w]; tot += s_ws[w]; }
    int pos = woff + incl - cnt;
    int rm = s_repmin;
    int rm_eff = (rm < NPTS) ? rm : 0x7fffffff;

    float xv[8], yv[8], zv[8];
    *(float4*)&xv[0] = *(const float4*)(xb + n0);
    *(float4*)&xv[4] = *(const float4*)(xb + n0 + 4);
    *(float4*)&yv[0] = *(const float4*)(xb + NPTS + n0);
    *(float4*)&yv[4] = *(const float4*)(xb + NPTS + n0 + 4);
    *(float4*)&zv[0] = *(const float4*)(xb + 2 * NPTS + n0);
    *(float4*)&zv[4] = *(const float4*)(xb + 2 * NPTS + n0 + 4);
#pragma unroll
    for (int j = 0; j < 8; j++) {
        if (keep[j]) {
            int fin = pos + ((n0 + j > rm_eff) ? 1 : 0);  // kept f==1 -> raw coords exact
            if (fin < CCAP)                               // overflow: don't corrupt neighbor
                c4[fin] = make_float4(xv[j], yv[j], zv[j], 0.0f);
            pos++;
        }
    }
    if (tid == 0) {
        int M = tot;
        if (rm < NPTS) {
            if (rm < CCAP)
                c4[rm] = make_float4(__fmul_rn(0.0f, xb[rm]),          // signed zeros exact
                                     __fmul_rn(0.0f, xb[NPTS + rm]),
                                     __fmul_rn(0.0f, xb[2 * NPTS + rm]), 0.0f);
            M++;
        }
        hdr[blk * 2] = M;
        hdr[blk * 2 + 1] = (rm < NPTS) ? rm : -1;
    }
}

// ---------------------------------------------------------------------------
// FPS stage 2: 256 threads / 4 waves per (b,grp), 17 slots/lane in regs
// (R3-proven allocation, VGPR~96). Serial chain per iteration: update (ALU,
// 4 SIMDs parallel) -> DPP u64 max to lane 63 (VALU) -> 1 LDS write ->
// ONE barrier (lgkm-only: outputs are buffered in LDS, flushed at the end,
// so no vmcnt drain) -> broadcast read of 4 keys -> ds_read_b128 coords.
// ---------------------------------------------------------------------------
__global__ __launch_bounds__(256, 1) void fps_iter(
    const float* __restrict__ attn,
    const float4* __restrict__ cxyz,
    const int* __restrict__ hdr,
    float* __restrict__ out0, float* __restrict__ out2)
{
    int blk = blockIdx.x;
    int b = blk >> 1, grp = blk & 1;
    int K = grp ? 384 : 128;
    int soff = grp ? 128 : 0;
    int M = hdr[blk * 2];
    int repslot = hdr[blk * 2 + 1];   // == rm, or -1
    if (M > CCAP) return;             // fps_kernel fallback covers this block
    int tid = threadIdx.x, lane = tid & 63, wid = tid >> 6;

    const float4* cb = cxyz + (size_t)blk * CCAP;
    __shared__ float4 sc[CCAP];                       // 68 KB coord table
    __shared__ float4 s_obuf[384];                    // output staging
    __shared__ __align__(16) unsigned long long s_red[2][4];

    float px[SLOTS], py[SLOTS], pz[SLOTS], md[SLOTS];
#pragma unroll
    for (int i = 0; i < SLOTS; i++) {
        int sl = i * 256 + tid;
        bool v = sl < M;
        float4 c = v ? cb[sl] : make_float4(0.f, 0.f, 0.f, 0.f);
        px[i] = c.x; py[i] = c.y; pz[i] = c.z;
        sc[sl] = c;
        md[i] = v ? 1e10f : -1.0f;    // invalid: d2>=0 keeps -1, never beats a valid slot
    }
    // slot 0 == original index 0 always (kept idx<rm sit at pos==idx; rm==0 -> rep at 0)
    float4 c0 = cb[0];
    float lx = c0.x, ly = c0.y, lz = c0.z;
    float a_last = attn[(size_t)b * NPTS];
    float kept_a = grp ? 0.0f : 1.0f;
    float rep_a  = grp ? 1.0f : 0.0f;

    for (int k = 0; k < K; k++) {
        if (tid == 0) s_obuf[k] = make_float4(lx, ly, lz, a_last);
        if (k == K - 1) break;

        float bv = -1.0f; int bslot = 0x7fffffff;
#pragma unroll
        for (int i = 0; i < SLOTS; i++) {
            float d2 = d2_exact(px[i], py[i], pz[i], lx, ly, lz);
            md[i] = fminf(md[i], d2);
            int sl = i * 256 + tid;
            bool w = (md[i] > bv) || ((md[i] == bv) && (sl < bslot));
            bv = w ? md[i] : bv;          // ascending sl scan + explicit tiebreak ==
            bslot = w ? sl : bslot;       // numpy argmax first-occurrence (slot==index order)
        }
        unsigned long long key = (bv >= 0.0f)
            ? (((unsigned long long)__float_as_uint(bv) << 32) | (unsigned)(~bslot))
            : 0ull;
        key = dpp_max_u64<0x111>(key);
        key = dpp_max_u64<0x112>(key);
        key = dpp_max_u64<0x114>(key);
        key = dpp_max_u64<0x118>(key);
        key = dpp_max_u64<0x142>(key);
        key = dpp_max_u64<0x143>(key);    // lane 63 = wave max
        int buf = k & 1;
        if (lane == 63) s_red[buf][wid] = key;
        __syncthreads();                  // lgkm-only drain: no global ops in flight

        const unsigned long long* rp = s_red[buf];  // broadcast reads (conflict-free)
        unsigned long long k0 = rp[0], k1 = rp[1], k2 = rp[2], k3 = rp[3];
        unsigned long long m01 = (k0 > k1) ? k0 : k1;
        unsigned long long m23 = (k2 > k3) ? k2 : k3;
        unsigned long long g = (m01 > m23) ? m01 : m23;
        int wslot = (int)(~(unsigned)g);
        float4 wc = sc[wslot];            // ds_read_b128, broadcast
        lx = wc.x; ly = wc.y; lz = wc.z;
        a_last = (wslot == repslot) ? rep_a : kept_a;
    }
    __syncthreads();
    for (int k2 = tid; k2 < K; k2 += 256) {
        float4 o = s_obuf[k2];
        int sg = soff + k2;
        out0[(size_t)b * 3 * S_TOT + sg] = o.x;
        out0[(size_t)b * 3 * S_TOT + S_TOT + sg] = o.y;
        out0[(size_t)b * 3 * S_TOT + 2 * S_TOT + sg] = o.z;
        out2[(size_t)b * S_TOT + sg] = o.w;
    }
}

// ---------------------------------------------------------------------------
// Fallback FPS over all 8192 points. Runs only if a block overflowed CCAP
// (|kept-4096| > 255, ~5.7 sigma) or ws too small.
// ---------------------------------------------------------------------------
__global__ __launch_bounds__(1024, 1) void fps_kernel(
    const float* __restrict__ xyz, const float* __restrict__ attn,
    const int* __restrict__ hdr,
    float* __restrict__ out0, float* __restrict__ out2)
{
    int blk = blockIdx.x;
    if (hdr != nullptr && hdr[blk * 2] <= CCAP) return;
    int b = blk >> 1, grp = blk & 1;
    int K = grp ? 384 : 128;
    int soff = grp ? 128 : 0;
    int tid = threadIdx.x, lane = tid & 63, wid = tid >> 6;
    const float* xb = xyz + (size_t)b * 3 * NPTS;
    const float* ab = attn + (size_t)b * NPTS;

    float px[8], py[8], pz[8], md[8];
#pragma unroll
    for (int i = 0; i < 8; i++) {
        int n = tid + i * 1024;
        float a = ab[n];
        float f = grp ? __fsub_rn(1.0f, a) : a;
        px[i] = __fmul_rn(f, xb[n]);
        py[i] = __fmul_rn(f, xb[NPTS + n]);
        pz[i] = __fmul_rn(f, xb[2 * NPTS + n]);
        md[i] = 1e10f;
    }
    __shared__ unsigned long long s_red[2][16];
    float a_last = ab[0];
    float f0 = grp ? __fsub_rn(1.0f, a_last) : a_last;
    float lx = __fmul_rn(f0, xb[0]);
    float ly = __fmul_rn(f0, xb[NPTS]);
    float lz = __fmul_rn(f0, xb[2 * NPTS]);

    for (int k = 0; k < K; k++) {
        if (tid == 0) {
            int sg = soff + k;
            out0[(size_t)b * 3 * S_TOT + sg] = lx;
            out0[(size_t)b * 3 * S_TOT + S_TOT + sg] = ly;
            out0[(size_t)b * 3 * S_TOT + 2 * S_TOT + sg] = lz;
            out2[(size_t)b * S_TOT + sg] = a_last;
        }
        if (k == K - 1) break;
        float bv = -1.0f; int bi = 0;
#pragma unroll
        for (int i = 0; i < 8; i++) {
            float d2 = d2_exact(px[i], py[i], pz[i], lx, ly, lz);
            md[i] = fminf(md[i], d2);
            if (md[i] > bv) { bv = md[i]; bi = tid + i * 1024; }
        }
        unsigned long long best =
            ((unsigned long long)__float_as_uint(bv) << 32) | (unsigned)(~bi);
#pragma unroll
        for (int off = 32; off >= 1; off >>= 1) {
            unsigned long long o = __shfl_down(best, off);
            best = (o > best) ? o : best;
        }
        if (lane == 0) s_red[k & 1][wid] = best;
        __syncthreads();
        unsigned long long r = (lane < 16) ? s_red[k & 1][lane] : 0ull;
#pragma unroll
        for (int off = 8; off >= 1; off >>= 1) {
            unsigned long long o = __shfl_down(r, off);
            r = (o > r) ? o : r;
        }
        r = __shfl(r, 0);
        int n = (int)(~(unsigned)r);
        a_last = ab[n];
        float fl = grp ? __fsub_rn(1.0f, a_last) : a_last;
        lx = __fmul_rn(fl, xb[n]);
        ly = __fmul_rn(fl, xb[NPTS + n]);
        lz = __fmul_rn(fl, xb[2 * NPTS + n]);
    }
}

// ---------------------------------------------------------------------------
// points [B,64,N] -> ptsT [B,N,64]
// ---------------------------------------------------------------------------
__global__ void transpose_pts(const float* __restrict__ pts, float* __restrict__ ptsT) {
    __shared__ float t[64][65];
    int b = blockIdx.y;
    int n0 = blockIdx.x * 64;
    int tx = threadIdx.x, ty = threadIdx.y;
    for (int c = ty; c < 64; c += 4)
        t[c][tx] = pts[((size_t)b * DFEAT + c) * NPTS + n0 + tx];
    __syncthreads();
    for (int r = ty; r < 64; r += 4)
        ptsT[((size_t)b * NPTS + n0 + r) * DFEAT + tx] = t[tx][r];
}

// w0 [64][67] -> w0T [67][64]; w1 [64][64] -> w1T [64][64]
__global__ void transpose_w(const float* __restrict__ w0, const float* __restrict__ w1,
                            float* __restrict__ w0T, float* __restrict__ w1T) {
    int t = blockIdx.x * 256 + threadIdx.x;
    if (t < INCH * 64) { int o = t & 63, c = t >> 6; w0T[c * 64 + o] = w0[o * INCH + c]; }
    if (t < 64 * 64)   { int o = t & 63, c = t >> 6; w1T[c * 64 + o] = w1[o * 64 + c]; }
}

// ---------------------------------------------------------------------------
// Ball query + 3-layer MLP + max over samples. One wave per query.
// LDS = 8.4 KB (h1 staged 32 channels at a time) -> 16 blocks/CU = 4 waves/SIMD.
// Single-wave block: no __syncthreads needed (compiler lgkmcnt orders own-wave
// LDS RAW). Epilogue max-reduce via DPP (VALU) instead of ds_bpermute shuffles.
// ---------------------------------------------------------------------------
__global__ __launch_bounds__(64, 1) void ball_mlp(
    const float* __restrict__ xyz,
    const float* __restrict__ pts,
    const float* __restrict__ ptsT,
    int use_ptsT,
    const float* __restrict__ w0T, const float* __restrict__ w1T, int use_wT,
    const float* __restrict__ w0, const float* __restrict__ b0,
    const float* __restrict__ w1, const float* __restrict__ b1,
    const float* __restrict__ w2, const float* __restrict__ b2,
    const float* __restrict__ out0,
    float* __restrict__ out1)
{
    const float R2 = (float)(0.4 * 0.4);   // 0x3E23D70A — NOT 0.4f*0.4f
    int q = blockIdx.x;
    int b = q >> 9;
    int sg = q & 511;
    int lane = threadIdx.x;

    const float* xb = xyz + (size_t)b * 3 * NPTS;
    float qx = out0[(size_t)b * 3 * S_TOT + sg];
    float qy = out0[(size_t)b * 3 * S_TOT + S_TOT + sg];
    float qz = out0[(size_t)b * 3 * S_TOT + 2 * S_TOT + sg];

    __shared__ int s_idx[NSAMP];
    __shared__ float s_h[32 * 64];   // half of h1, [c][lane]
    int cnt = 0;
#pragma unroll 4
    for (int base = 0; base < NPTS; base += 64) {   // no early exit: loads independent
        int n = base + lane;
        float d2 = d2_exact(qx, qy, qz, xb[n], xb[NPTS + n], xb[2 * NPTS + n]);
        bool flag = d2 < R2;
        unsigned long long m = __ballot(flag);
        int pos = cnt + (int)__popcll(m & ((1ull << lane) - 1ull));
        if (flag && pos < NSAMP) s_idx[pos] = n;
        cnt += (int)__popcll(m);
    }
    if (cnt > NSAMP) cnt = NSAMP;

    int nb = (lane < cnt) ? s_idx[lane] : -1;
    float nx_ = 0.f, ny_ = 0.f, nz_ = 0.f;
    if (nb >= 0) { nx_ = xb[nb]; ny_ = xb[NPTS + nb]; nz_ = xb[2 * NPTS + nb]; }
    float fx = nx_ - qx, fy = ny_ - qy, fz = nz_ - qz;   // pad: -new_xyz (ref semantics)
    int row = (nb < 0) ? (NPTS - 1) : nb;                // torch -1 wraps to last point

    // ---- layer 1: 67 -> 64 ----
    float h1[64];
    if (use_wT) {
#pragma unroll
        for (int o = 0; o < 64; o++) {
            float a = __builtin_fmaf(w0T[o], fx, b0[o]);
            a = __builtin_fmaf(w0T[64 + o], fy, a);
            h1[o] = __builtin_fmaf(w0T[128 + o], fz, a);
        }
        if (use_ptsT) {
            const float* prow = ptsT + ((size_t)b * NPTS + row) * DFEAT;
#pragma unroll 1
            for (int c = 0; c < 64; c += 4) {
                float4 f4 = *(const float4*)(prow + c);
                const float* wr = w0T + (3 + c) * 64;
#pragma unroll
                for (int o = 0; o < 64; o++) {
                    float a = __builtin_fmaf(wr[o], f4.x, h1[o]);
                    a = __builtin_fmaf(wr[64 + o], f4.y, a);
                    a = __builtin_fmaf(wr[128 + o], f4.z, a);
                    h1[o] = __builtin_fmaf(wr[192 + o], f4.w, a);
                }
            }
        } else {
            const float* pb = pts + (size_t)b * DFEAT * NPTS + row;
#pragma unroll 1
            for (int c = 0; c < 64; c++) {
                float f = pb[(size_t)c * NPTS];
                const float* wr = w0T + (3 + c) * 64;
#pragma unroll
                for (int o = 0; o < 64; o++)
                    h1[o] = __builtin_fmaf(wr[o], f, h1[o]);
            }
        }
    } else {
#pragma unroll
        for (int o = 0; o < 64; o++) {
            float a = __builtin_fmaf(w0[o * INCH + 0], fx, b0[o]);
            a = __builtin_fmaf(w0[o * INCH + 1], fy, a);
            h1[o] = __builtin_fmaf(w0[o * INCH + 2], fz, a);
        }
        const float* pb = pts + (size_t)b * DFEAT * NPTS + row;
#pragma unroll 1
        for (int c = 0; c < 64; c++) {
            float f = use_ptsT ? ptsT[((size_t)b * NPTS + row) * DFEAT + c]
                               : pb[(size_t)c * NPTS];
#pragma unroll
            for (int o = 0; o < 64; o++)
                h1[o] = __builtin_fmaf(w0[o * INCH + 3 + c], f, h1[o]);
        }
    }

    // stage lo half (c=0..31) to LDS; hold hi half in 32 statically-indexed regs
#pragma unroll
    for (int c = 0; c < 32; c++) s_h[c * 64 + lane] = fmaxf(h1[c], 0.0f);
    float h1h[32];
#pragma unroll
    for (int c = 0; c < 32; c++) h1h[c] = fmaxf(h1[32 + c], 0.0f);

    // ---- layer 2: 64 -> 64, c ascending (lo from LDS, then hi) ----
    float h2[64];
#pragma unroll
    for (int o = 0; o < 64; o++) h2[o] = b1[o];
#pragma unroll 1
    for (int c = 0; c < 32; c++) {
        float hc = s_h[c * 64 + lane];
        const float* wr = use_wT ? (w1T + c * 64) : nullptr;
#pragma unroll
        for (int o = 0; o < 64; o++)
            h2[o] = __builtin_fmaf(use_wT ? wr[o] : w1[o * 64 + c], hc, h2[o]);
    }
    // move hi half into the same LDS space, then consume (keeps c order 32..63)
#pragma unroll
    for (int c = 0; c < 32; c++) s_h[c * 64 + lane] = h1h[c];
#pragma unroll 1
    for (int c = 0; c < 32; c++) {
        float hc = s_h[c * 64 + lane];
        const float* wr = use_wT ? (w1T + (32 + c) * 64) : nullptr;
#pragma unroll
        for (int o = 0; o < 64; o++)
            h2[o] = __builtin_fmaf(use_wT ? wr[o] : w1[o * 64 + (32 + c)], hc, h2[o]);
    }
#pragma unroll
    for (int o = 0; o < 64; o++) h2[o] = fmaxf(h2[o], 0.0f);

    // ---- layer 3: 64 -> 128, relu, DPP lane-max (result in lane 63) ----
#pragma unroll 2
    for (int o = 0; o < 128; o++) {
        const float* wr = w2 + o * 64;
        float acc = b2[o];
#pragma unroll
        for (int c = 0; c < 64; c++) acc = __builtin_fmaf(wr[c], h2[c], acc);
        acc = fmaxf(acc, 0.0f);   // relu(max) == max(relu): monotone
        acc = dpp_max_f32<0x111>(acc);
        acc = dpp_max_f32<0x112>(acc);
        acc = dpp_max_f32<0x114>(acc);
        acc = dpp_max_f32<0x118>(acc);
        acc = dpp_max_f32<0x142>(acc);
        acc = dpp_max_f32<0x143>(acc);
        if (lane == 63) out1[((size_t)(b * 128 + o)) * S_TOT + sg] = acc;
    }
}

extern "C" void kernel_launch(void* const* d_in, const int* in_sizes, int n_in,
                              void* d_out, int out_size, void* d_ws, size_t ws_size,
                              hipStream_t stream) {
    const float* xyz  = (const float*)d_in[0];
    const float* pts  = (const float*)d_in[1];
    const float* attn = (const float*)d_in[2];
    const float* w0 = (const float*)d_in[3];
    const float* b0 = (const float*)d_in[4];
    const float* w1 = (const float*)d_in[5];
    const float* b1 = (const float*)d_in[6];
    const float* w2 = (const float*)d_in[7];
    const float* b2 = (const float*)d_in[8];

    float* out0 = (float*)d_out;                    // [B,3,S]   = 12288
    float* out1 = out0 + (size_t)NB * 3 * S_TOT;    // [B,128,S] = 524288
    float* out2 = out1 + (size_t)NB * 128 * S_TOT;  // [B,1,S]   = 4096

    // ws layout (floats): w0T(4288) w1T(4096) pad->8448 | ptsT 4194304 |
    //   cxyz 16*CCAP*4 | hdr 32 ints
    float*  w0T  = (float*)d_ws;
    float*  w1T  = w0T + INCH * 64;
    float*  ptsT = w0T + 8448;
    float4* cxyz = (float4*)(ptsT + (size_t)NB * NPTS * DFEAT);
    int*    hdr  = (int*)(cxyz + (size_t)16 * CCAP);

    const size_t wT_f   = 8448;
    const size_t ptsT_f = (size_t)NB * NPTS * DFEAT;
    const size_t full_f = wT_f + ptsT_f + (size_t)16 * CCAP * 4 + 32;
    int use_wT   = (ws_size >= wT_f * 4) ? 1 : 0;
    int use_ptsT = (ws_size >= (wT_f + ptsT_f) * 4) ? 1 : 0;
    int use_fps2 = (ws_size >= full_f * 4) ? 1 : 0;

    if (use_fps2) {
        fps_compact<<<16, 1024, 0, stream>>>(xyz, attn, cxyz, hdr);
        fps_iter<<<16, 256, 0, stream>>>(attn, cxyz, hdr, out0, out2);
        fps_kernel<<<16, 1024, 0, stream>>>(xyz, attn, hdr, out0, out2);  // gated fallback
    } else {
        fps_kernel<<<16, 1024, 0, stream>>>(xyz, attn, nullptr, out0, out2);
    }
    if (use_wT)
        transpose_w<<<(INCH * 64 + 255) / 256, 256, 0, stream>>>(w0, w1, w0T, w1T);
    if (use_ptsT)
        transpose_pts<<<dim3(NPTS / 64, NB), dim3(64, 4), 0, stream>>>(pts, ptsT);
    ball_mlp<<<NB * S_TOT, 64, 0, stream>>>(xyz, pts, ptsT, use_ptsT,
                                            w0T, w1T, use_wT,
                                            w0, b0, w1, b1, w2, b2, out0, out1);
}

// Round 6
// 690.723 us; speedup vs baseline: 1.7362x; 1.5699x over previous
//
#include <hip/hip_runtime.h>
#include <cstdint>
#include <cstddef>

#define NB 8
#define NPTS 8192
#define S_TOT 512
#define NSAMP 64
#define DFEAT 64
#define INCH 67
#define SLOTS 17
#define CCAP (SLOTS * 256)   // 4352 compacted slots per (b,grp)

typedef __attribute__((ext_vector_type(8))) short v8s;
typedef __attribute__((ext_vector_type(4))) short v4s;
typedef __attribute__((ext_vector_type(4))) float v4f;

// exact (numpy-matching) squared distance: (a-b) per component, square, sum as (x+y)+z
__device__ __forceinline__ float d2_exact(float ax, float ay, float az,
                                          float bx, float by, float bz) {
    float dx = __fsub_rn(ax, bx);
    float dy = __fsub_rn(ay, by);
    float dz = __fsub_rn(az, bz);
    return __fadd_rn(__fadd_rn(__fmul_rn(dx, dx), __fmul_rn(dy, dy)), __fmul_rn(dz, dz));
}

// fp32 -> bf16 round-to-nearest-even
__device__ __forceinline__ unsigned short f2b(float f) {
    unsigned u = __float_as_uint(f);
    return (unsigned short)((u + 0x7fffu + ((u >> 16) & 1u)) >> 16);
}

template <int CTRL>
__device__ __forceinline__ unsigned long long dpp_max_u64(unsigned long long k) {
    int lo = (int)(unsigned)(k & 0xffffffffull);
    int hi = (int)(unsigned)(k >> 32);
    int slo = __builtin_amdgcn_update_dpp(lo, lo, CTRL, 0xf, 0xf, false);
    int shi = __builtin_amdgcn_update_dpp(hi, hi, CTRL, 0xf, 0xf, false);
    unsigned long long o = ((unsigned long long)(unsigned)shi << 32) | (unsigned)slo;
    return (o > k) ? o : k;
}

// ---------------------------------------------------------------------------
// FPS stage 1 (unchanged from R5): compact + sort-preserving rep insertion.
// ---------------------------------------------------------------------------
__global__ __launch_bounds__(1024) void fps_compact(
    const float* __restrict__ xyz, const float* __restrict__ attn,
    float4* __restrict__ cxyz, int* __restrict__ hdr)
{
    int blk = blockIdx.x;
    int b = blk >> 1, grp = blk & 1;
    const float* xb = xyz + (size_t)b * 3 * NPTS;
    const float* ab = attn + (size_t)b * NPTS;
    float4* c4 = cxyz + (size_t)blk * CCAP;

    int tid = threadIdx.x, lane = tid & 63, wid = tid >> 6;
    int n0 = tid * 8;

    __shared__ int s_repmin;
    __shared__ int s_ws[16];
    if (tid == 0) s_repmin = NPTS;
    __syncthreads();

    float av[8];
    *(float4*)&av[0] = *(const float4*)(ab + n0);
    *(float4*)&av[4] = *(const float4*)(ab + n0 + 4);
    int cnt = 0, mymin = NPTS;
    bool keep[8];
#pragma unroll
    for (int j = 0; j < 8; j++) {
        keep[j] = grp ? (av[j] == 0.0f) : (av[j] != 0.0f);
        cnt += keep[j] ? 1 : 0;
        if (!keep[j] && n0 + j < mymin) mymin = n0 + j;
    }
    if (mymin < NPTS) atomicMin(&s_repmin, mymin);

    int incl = cnt;
#pragma unroll
    for (int off = 1; off <= 32; off <<= 1) {
        int t = __shfl_up(incl, off);
        if (lane >= off) incl += t;
    }
    if (lane == 63) s_ws[wid] = incl;
    __syncthreads();
    int woff = 0, tot = 0;
#pragma unroll
    for (int w = 0; w < 16; w++) { if (w < wid) woff += s_ws[w]; tot += s_ws[w]; }
    int pos = woff + incl - cnt;
    int rm = s_repmin;
    int rm_eff = (rm < NPTS) ? rm : 0x7fffffff;

    float xv[8], yv[8], zv[8];
    *(float4*)&xv[0] = *(const float4*)(xb + n0);
    *(float4*)&xv[4] = *(const float4*)(xb + n0 + 4);
    *(float4*)&yv[0] = *(const float4*)(xb + NPTS + n0);
    *(float4*)&yv[4] = *(const float4*)(xb + NPTS + n0 + 4);
    *(float4*)&zv[0] = *(const float4*)(xb + 2 * NPTS + n0);
    *(float4*)&zv[4] = *(const float4*)(xb + 2 * NPTS + n0 + 4);
#pragma unroll
    for (int j = 0; j < 8; j++) {
        if (keep[j]) {
            int fin = pos + ((n0 + j > rm_eff) ? 1 : 0);
            if (fin < CCAP)
                c4[fin] = make_float4(xv[j], yv[j], zv[j], 0.0f);
            pos++;
        }
    }
    if (tid == 0) {
        int M = tot;
        if (rm < NPTS) {
            if (rm < CCAP)
                c4[rm] = make_float4(__fmul_rn(0.0f, xb[rm]),
                                     __fmul_rn(0.0f, xb[NPTS + rm]),
                                     __fmul_rn(0.0f, xb[2 * NPTS + rm]), 0.0f);
            M++;
        }
        hdr[blk * 2] = M;
        hdr[blk * 2 + 1] = (rm < NPTS) ? rm : -1;
    }
}

// ---------------------------------------------------------------------------
// FPS stage 2 (unchanged from R5).
// ---------------------------------------------------------------------------
__global__ __launch_bounds__(256, 1) void fps_iter(
    const float* __restrict__ attn,
    const float4* __restrict__ cxyz,
    const int* __restrict__ hdr,
    float* __restrict__ out0, float* __restrict__ out2)
{
    int blk = blockIdx.x;
    int b = blk >> 1, grp = blk & 1;
    int K = grp ? 384 : 128;
    int soff = grp ? 128 : 0;
    int M = hdr[blk * 2];
    int repslot = hdr[blk * 2 + 1];
    if (M > CCAP) return;
    int tid = threadIdx.x, lane = tid & 63, wid = tid >> 6;

    const float4* cb = cxyz + (size_t)blk * CCAP;
    __shared__ float4 sc[CCAP];
    __shared__ float4 s_obuf[384];
    __shared__ __align__(16) unsigned long long s_red[2][4];

    float px[SLOTS], py[SLOTS], pz[SLOTS], md[SLOTS];
#pragma unroll
    for (int i = 0; i < SLOTS; i++) {
        int sl = i * 256 + tid;
        bool v = sl < M;
        float4 c = v ? cb[sl] : make_float4(0.f, 0.f, 0.f, 0.f);
        px[i] = c.x; py[i] = c.y; pz[i] = c.z;
        sc[sl] = c;
        md[i] = v ? 1e10f : -1.0f;
    }
    float4 c0 = cb[0];
    float lx = c0.x, ly = c0.y, lz = c0.z;
    float a_last = attn[(size_t)b * NPTS];
    float kept_a = grp ? 0.0f : 1.0f;
    float rep_a  = grp ? 1.0f : 0.0f;

    for (int k = 0; k < K; k++) {
        if (tid == 0) s_obuf[k] = make_float4(lx, ly, lz, a_last);
        if (k == K - 1) break;

        float bv = -1.0f; int bslot = 0x7fffffff;
#pragma unroll
        for (int i = 0; i < SLOTS; i++) {
            float d2 = d2_exact(px[i], py[i], pz[i], lx, ly, lz);
            md[i] = fminf(md[i], d2);
            int sl = i * 256 + tid;
            bool w = (md[i] > bv) || ((md[i] == bv) && (sl < bslot));
            bv = w ? md[i] : bv;
            bslot = w ? sl : bslot;
        }
        unsigned long long key = (bv >= 0.0f)
            ? (((unsigned long long)__float_as_uint(bv) << 32) | (unsigned)(~bslot))
            : 0ull;
        key = dpp_max_u64<0x111>(key);
        key = dpp_max_u64<0x112>(key);
        key = dpp_max_u64<0x114>(key);
        key = dpp_max_u64<0x118>(key);
        key = dpp_max_u64<0x142>(key);
        key = dpp_max_u64<0x143>(key);
        int buf = k & 1;
        if (lane == 63) s_red[buf][wid] = key;
        __syncthreads();

        const unsigned long long* rp = s_red[buf];
        unsigned long long k0 = rp[0], k1 = rp[1], k2 = rp[2], k3 = rp[3];
        unsigned long long m01 = (k0 > k1) ? k0 : k1;
        unsigned long long m23 = (k2 > k3) ? k2 : k3;
        unsigned long long g = (m01 > m23) ? m01 : m23;
        int wslot = (int)(~(unsigned)g);
        float4 wc = sc[wslot];
        lx = wc.x; ly = wc.y; lz = wc.z;
        a_last = (wslot == repslot) ? rep_a : kept_a;
    }
    __syncthreads();
    for (int k2 = tid; k2 < K; k2 += 256) {
        float4 o = s_obuf[k2];
        int sg = soff + k2;
        out0[(size_t)b * 3 * S_TOT + sg] = o.x;
        out0[(size_t)b * 3 * S_TOT + S_TOT + sg] = o.y;
        out0[(size_t)b * 3 * S_TOT + 2 * S_TOT + sg] = o.z;
        out2[(size_t)b * S_TOT + sg] = o.w;
    }
}

// ---------------------------------------------------------------------------
// Fallback FPS (unchanged): only if a block overflowed CCAP or ws too small.
// ---------------------------------------------------------------------------
__global__ __launch_bounds__(1024, 1) void fps_kernel(
    const float* __restrict__ xyz, const float* __restrict__ attn,
    const int* __restrict__ hdr,
    float* __restrict__ out0, float* __restrict__ out2)
{
    int blk = blockIdx.x;
    if (hdr != nullptr && hdr[blk * 2] <= CCAP) return;
    int b = blk >> 1, grp = blk & 1;
    int K = grp ? 384 : 128;
    int soff = grp ? 128 : 0;
    int tid = threadIdx.x, lane = tid & 63, wid = tid >> 6;
    const float* xb = xyz + (size_t)b * 3 * NPTS;
    const float* ab = attn + (size_t)b * NPTS;

    float px[8], py[8], pz[8], md[8];
#pragma unroll
    for (int i = 0; i < 8; i++) {
        int n = tid + i * 1024;
        float a = ab[n];
        float f = grp ? __fsub_rn(1.0f, a) : a;
        px[i] = __fmul_rn(f, xb[n]);
        py[i] = __fmul_rn(f, xb[NPTS + n]);
        pz[i] = __fmul_rn(f, xb[2 * NPTS + n]);
        md[i] = 1e10f;
    }
    __shared__ unsigned long long s_red[2][16];
    float a_last = ab[0];
    float f0 = grp ? __fsub_rn(1.0f, a_last) : a_last;
    float lx = __fmul_rn(f0, xb[0]);
    float ly = __fmul_rn(f0, xb[NPTS]);
    float lz = __fmul_rn(f0, xb[2 * NPTS]);

    for (int k = 0; k < K; k++) {
        if (tid == 0) {
            int sg = soff + k;
            out0[(size_t)b * 3 * S_TOT + sg] = lx;
            out0[(size_t)b * 3 * S_TOT + S_TOT + sg] = ly;
            out0[(size_t)b * 3 * S_TOT + 2 * S_TOT + sg] = lz;
            out2[(size_t)b * S_TOT + sg] = a_last;
        }
        if (k == K - 1) break;
        float bv = -1.0f; int bi = 0;
#pragma unroll
        for (int i = 0; i < 8; i++) {
            float d2 = d2_exact(px[i], py[i], pz[i], lx, ly, lz);
            md[i] = fminf(md[i], d2);
            if (md[i] > bv) { bv = md[i]; bi = tid + i * 1024; }
        }
        unsigned long long best =
            ((unsigned long long)__float_as_uint(bv) << 32) | (unsigned)(~bi);
#pragma unroll
        for (int off = 32; off >= 1; off >>= 1) {
            unsigned long long o = __shfl_down(best, off);
            best = (o > best) ? o : best;
        }
        if (lane == 0) s_red[k & 1][wid] = best;
        __syncthreads();
        unsigned long long r = (lane < 16) ? s_red[k & 1][lane] : 0ull;
#pragma unroll
        for (int off = 8; off >= 1; off >>= 1) {
            unsigned long long o = __shfl_down(r, off);
            r = (o > r) ? o : r;
        }
        r = __shfl(r, 0);
        int n = (int)(~(unsigned)r);
        a_last = ab[n];
        float fl = grp ? __fsub_rn(1.0f, a_last) : a_last;
        lx = __fmul_rn(fl, xb[n]);
        ly = __fmul_rn(fl, xb[NPTS + n]);
        lz = __fmul_rn(fl, xb[2 * NPTS + n]);
    }
}

// ---------------------------------------------------------------------------
// points [B,64,N] fp32 -> ptsTh [B,N,64] bf16 (tiled via LDS)
// ---------------------------------------------------------------------------
__global__ void transpose_pts(const float* __restrict__ pts,
                              unsigned short* __restrict__ ptsTh) {
    __shared__ float t[64][65];
    int b = blockIdx.y;
    int n0 = blockIdx.x * 64;
    int tx = threadIdx.x, ty = threadIdx.y;
    for (int c = ty; c < 64; c += 4)
        t[c][tx] = pts[((size_t)b * DFEAT + c) * NPTS + n0 + tx];
    __syncthreads();
    for (int r = ty; r < 64; r += 4)
        ptsTh[((size_t)b * NPTS + n0 + r) * DFEAT + tx] = f2b(t[tx][r]);
}

// ---------------------------------------------------------------------------
// Pack weights into MFMA B-fragment order (bf16), one tile = 64 lanes x 8.
// B-frag layout: lane holds B[k][n] with n = lane&15, k = (lane>>4)*8 + j.
// Tiles: L1: t=kt*4+nt (kt<3, nt<4), K-mapping k<64 -> w0 col 3+k (pts feats),
//        k=64..66 -> w0 col k-64 (xyz), k>=67 -> 0.   X rows use the SAME
//        order: [feats(64), fx,fy,fz, 0...].
//        L2: t=12+kt*4+nt (kt<2).   L3: t=20+kt*8+nt (kt<2, nt<8).
// ---------------------------------------------------------------------------
__global__ void pack_w(const float* __restrict__ w0, const float* __restrict__ w1,
                       const float* __restrict__ w2, unsigned short* __restrict__ wp) {
    int t = blockIdx.x, l = threadIdx.x;
    int kq = (l >> 4) * 8, n16 = l & 15;
    unsigned short o[8];
#pragma unroll
    for (int j = 0; j < 8; j++) {
        float v;
        if (t < 12) {
            int kt = t >> 2, nt = t & 3;
            int k = kt * 32 + kq + j, n = nt * 16 + n16;
            v = (k < 64) ? w0[n * INCH + 3 + k] : (k < 67 ? w0[n * INCH + (k - 64)] : 0.0f);
        } else if (t < 20) {
            int tt = t - 12, kt = tt >> 2, nt = tt & 3;
            v = w1[(nt * 16 + n16) * 64 + kt * 32 + kq + j];
        } else {
            int tt = t - 20, kt = tt >> 3, nt = tt & 7;
            v = w2[(nt * 16 + n16) * 64 + kt * 32 + kq + j];
        }
        o[j] = f2b(v);
    }
    *(v8s*)&wp[(size_t)t * 512 + l * 8] = *(v8s*)o;
}

// ---------------------------------------------------------------------------
// Ball query + MFMA MLP + max. One wave per query.
// X[64 samples x 96(K-pad)] bf16 in LDS; weights pre-packed as B-frags
// (one coalesced dwordx4 per tile per wave -> 36 weight loads instead of ~4k).
// Layouts (m89/m120-verified): A[m=lane&15][k=(lane>>4)*8+j];
// C/D col=lane&15, row=(lane>>4)*4+reg. Bias folded into acc init.
// ---------------------------------------------------------------------------
__global__ __launch_bounds__(64, 2) void ball_mlp_mfma(
    const float* __restrict__ xyz,
    const unsigned short* __restrict__ ptsTh,
    const unsigned short* __restrict__ wp,
    const float* __restrict__ b0, const float* __restrict__ b1,
    const float* __restrict__ b2,
    const float* __restrict__ out0,
    float* __restrict__ out1)
{
    const float R2 = (float)(0.4 * 0.4);   // 0x3E23D70A — NOT 0.4f*0.4f
    int q = blockIdx.x;
    int b = q >> 9;
    int sg = q & 511;
    int lane = threadIdx.x;
    int col = lane & 15, quad = lane >> 4, kq = quad * 8;

    const float* xb = xyz + (size_t)b * 3 * NPTS;
    float qx = out0[(size_t)b * 3 * S_TOT + sg];
    float qy = out0[(size_t)b * 3 * S_TOT + S_TOT + sg];
    float qz = out0[(size_t)b * 3 * S_TOT + 2 * S_TOT + sg];

    __shared__ int s_idx[NSAMP];
    __shared__ short sX1[64 * 104];   // stride 104 bf16 (208 B, 16B-aligned, 2-way banks)
    __shared__ short sX2[64 * 72];    // stride 72 bf16 (144 B)

    // ---- ball query (R5-verified) ----
    int cnt = 0;
#pragma unroll 4
    for (int base = 0; base < NPTS; base += 64) {
        int n = base + lane;
        float d2 = d2_exact(qx, qy, qz, xb[n], xb[NPTS + n], xb[2 * NPTS + n]);
        bool flag = d2 < R2;
        unsigned long long m = __ballot(flag);
        int pos = cnt + (int)__popcll(m & ((1ull << lane) - 1ull));
        if (flag && pos < NSAMP) s_idx[pos] = n;
        cnt += (int)__popcll(m);
    }
    if (cnt > NSAMP) cnt = NSAMP;

    int nb = (lane < cnt) ? s_idx[lane] : -1;
    float nx_ = 0.f, ny_ = 0.f, nz_ = 0.f;
    if (nb >= 0) { nx_ = xb[nb]; ny_ = xb[NPTS + nb]; nz_ = xb[2 * NPTS + nb]; }
    float fx = nx_ - qx, fy = ny_ - qy, fz = nz_ - qz;   // pad rows: -new_xyz
    int row = (nb < 0) ? (NPTS - 1) : nb;                // torch -1 wraps to last

    // ---- stage X1 row (this lane = sample): [feats(64), fx,fy,fz, zeros] ----
    {
        const unsigned short* ph = ptsTh + ((size_t)b * NPTS + row) * DFEAT;
        short* xr = &sX1[lane * 104];
#pragma unroll
        for (int i = 0; i < 8; i++)
            *(v8s*)(xr + i * 8) = *(const v8s*)(ph + i * 8);
#pragma unroll
        for (int i = 0; i < 5; i++)
            *(v8s*)(xr + 64 + i * 8) = (v8s)0;           // zeros 64..104
        v4s xyzp;
        xyzp[0] = (short)f2b(fx); xyzp[1] = (short)f2b(fy);
        xyzp[2] = (short)f2b(fz); xyzp[3] = 0;
        *(v4s*)(xr + 64) = xyzp;                          // overwrite 64..67 (+pad 67)
    }

    const v8s* wpv = (const v8s*)wp;   // tile t -> wpv[t*64 + lane]

    // ---- layer 1: [64x96] x [96x64], 3 K-steps ----
    v4f acc[4][4];
#pragma unroll
    for (int nt = 0; nt < 4; nt++) {
        float bb = b0[nt * 16 + col];
#pragma unroll
        for (int mt = 0; mt < 4; mt++) acc[mt][nt] = (v4f){bb, bb, bb, bb};
    }
#pragma unroll
    for (int kt = 0; kt < 3; kt++) {
        v8s bf[4];
#pragma unroll
        for (int nt = 0; nt < 4; nt++) bf[nt] = wpv[(kt * 4 + nt) * 64 + lane];
#pragma unroll
        for (int mt = 0; mt < 4; mt++) {
            v8s a = *(const v8s*)&sX1[(mt * 16 + col) * 104 + kt * 32 + kq];
#pragma unroll
            for (int nt = 0; nt < 4; nt++)
                acc[mt][nt] = __builtin_amdgcn_mfma_f32_16x16x32_bf16(a, bf[nt], acc[mt][nt], 0, 0, 0);
        }
    }
    // relu + cvt + C-layout -> A-layout via LDS (X2, stride 72)
#pragma unroll
    for (int mt = 0; mt < 4; mt++)
#pragma unroll
        for (int nt = 0; nt < 4; nt++)
#pragma unroll
            for (int r = 0; r < 4; r++)
                sX2[(mt * 16 + quad * 4 + r) * 72 + nt * 16 + col] =
                    (short)f2b(fmaxf(acc[mt][nt][r], 0.0f));

    // ---- layer 2: [64x64] x [64x64], 2 K-steps ----
#pragma unroll
    for (int nt = 0; nt < 4; nt++) {
        float bb = b1[nt * 16 + col];
#pragma unroll
        for (int mt = 0; mt < 4; mt++) acc[mt][nt] = (v4f){bb, bb, bb, bb};
    }
#pragma unroll
    for (int kt = 0; kt < 2; kt++) {
        v8s bf[4];
#pragma unroll
        for (int nt = 0; nt < 4; nt++) bf[nt] = wpv[(12 + kt * 4 + nt) * 64 + lane];
#pragma unroll
        for (int mt = 0; mt < 4; mt++) {
            v8s a = *(const v8s*)&sX2[(mt * 16 + col) * 72 + kt * 32 + kq];
#pragma unroll
            for (int nt = 0; nt < 4; nt++)
                acc[mt][nt] = __builtin_amdgcn_mfma_f32_16x16x32_bf16(a, bf[nt], acc[mt][nt], 0, 0, 0);
        }
    }
    // relu + cvt -> X3 (reuse sX1 storage, stride 72; L1 reads long done)
#pragma unroll
    for (int mt = 0; mt < 4; mt++)
#pragma unroll
        for (int nt = 0; nt < 4; nt++)
#pragma unroll
            for (int r = 0; r < 4; r++)
                sX1[(mt * 16 + quad * 4 + r) * 72 + nt * 16 + col] =
                    (short)f2b(fmaxf(acc[mt][nt][r], 0.0f));

    // ---- layer 3: [64x64] x [64x128], two passes of 4 N-tiles ----
#pragma unroll
    for (int p = 0; p < 2; p++) {
#pragma unroll
        for (int nt = 0; nt < 4; nt++) {
            float bb = b2[(p * 4 + nt) * 16 + col];
#pragma unroll
            for (int mt = 0; mt < 4; mt++) acc[mt][nt] = (v4f){bb, bb, bb, bb};
        }
#pragma unroll
        for (int kt = 0; kt < 2; kt++) {
            v8s bf[4];
#pragma unroll
            for (int nt = 0; nt < 4; nt++)
                bf[nt] = wpv[(20 + kt * 8 + p * 4 + nt) * 64 + lane];
#pragma unroll
            for (int mt = 0; mt < 4; mt++) {
                v8s a = *(const v8s*)&sX1[(mt * 16 + col) * 72 + kt * 32 + kq];
#pragma unroll
                for (int nt = 0; nt < 4; nt++)
                    acc[mt][nt] = __builtin_amdgcn_mfma_f32_16x16x32_bf16(a, bf[nt], acc[mt][nt], 0, 0, 0);
            }
        }
        // relu, max over rows (4 regs x 4 mt in-lane, then across quads), store
#pragma unroll
        for (int nt = 0; nt < 4; nt++) {
            float v = 0.0f;   // relu output >= 0
#pragma unroll
            for (int mt = 0; mt < 4; mt++)
#pragma unroll
                for (int r = 0; r < 4; r++)
                    v = fmaxf(v, acc[mt][nt][r]);
            v = fmaxf(v, __shfl_xor(v, 16));
            v = fmaxf(v, __shfl_xor(v, 32));
            if (lane < 16)
                out1[((size_t)(b * 128 + (p * 4 + nt) * 16 + lane)) * S_TOT + sg] = v;
        }
    }
}

// ---------------------------------------------------------------------------
// Fallback ball+MLP (no ws): R5 structure, raw strided gathers. Correct, slow.
// ---------------------------------------------------------------------------
__global__ __launch_bounds__(64, 1) void ball_mlp_fb(
    const float* __restrict__ xyz, const float* __restrict__ pts,
    const float* __restrict__ w0, const float* __restrict__ b0,
    const float* __restrict__ w1, const float* __restrict__ b1,
    const float* __restrict__ w2, const float* __restrict__ b2,
    const float* __restrict__ out0, float* __restrict__ out1)
{
    const float R2 = (float)(0.4 * 0.4);
    int q = blockIdx.x;
    int b = q >> 9, sg = q & 511, lane = threadIdx.x;
    const float* xb = xyz + (size_t)b * 3 * NPTS;
    float qx = out0[(size_t)b * 3 * S_TOT + sg];
    float qy = out0[(size_t)b * 3 * S_TOT + S_TOT + sg];
    float qz = out0[(size_t)b * 3 * S_TOT + 2 * S_TOT + sg];

    __shared__ int s_idx[NSAMP];
    __shared__ float s_h[32 * 64];
    int cnt = 0;
    for (int base = 0; base < NPTS; base += 64) {
        int n = base + lane;
        float d2 = d2_exact(qx, qy, qz, xb[n], xb[NPTS + n], xb[2 * NPTS + n]);
        bool flag = d2 < R2;
        unsigned long long m = __ballot(flag);
        int pos = cnt + (int)__popcll(m & ((1ull << lane) - 1ull));
        if (flag && pos < NSAMP) s_idx[pos] = n;
        cnt += (int)__popcll(m);
    }
    if (cnt > NSAMP) cnt = NSAMP;
    int nb = (lane < cnt) ? s_idx[lane] : -1;
    float nx_ = 0.f, ny_ = 0.f, nz_ = 0.f;
    if (nb >= 0) { nx_ = xb[nb]; ny_ = xb[NPTS + nb]; nz_ = xb[2 * NPTS + nb]; }
    float fx = nx_ - qx, fy = ny_ - qy, fz = nz_ - qz;
    int row = (nb < 0) ? (NPTS - 1) : nb;

    float h1[64];
#pragma unroll
    for (int o = 0; o < 64; o++) {
        float a = __builtin_fmaf(w0[o * INCH + 0], fx, b0[o]);
        a = __builtin_fmaf(w0[o * INCH + 1], fy, a);
        h1[o] = __builtin_fmaf(w0[o * INCH + 2], fz, a);
    }
    const float* pb = pts + (size_t)b * DFEAT * NPTS + row;
#pragma unroll 1
    for (int c = 0; c < 64; c++) {
        float f = pb[(size_t)c * NPTS];
#pragma unroll
        for (int o = 0; o < 64; o++)
            h1[o] = __builtin_fmaf(w0[o * INCH + 3 + c], f, h1[o]);
    }
#pragma unroll
    for (int c = 0; c < 32; c++) s_h[c * 64 + lane] = fmaxf(h1[c], 0.0f);
    float h1h[32];
#pragma unroll
    for (int c = 0; c < 32; c++) h1h[c] = fmaxf(h1[32 + c], 0.0f);

    float h2[64];
#pragma unroll
    for (int o = 0; o < 64; o++) h2[o] = b1[o];
#pragma unroll 1
    for (int c = 0; c < 32; c++) {
        float hc = s_h[c * 64 + lane];
#pragma unroll
        for (int o = 0; o < 64; o++)
            h2[o] = __builtin_fmaf(w1[o * 64 + c], hc, h2[o]);
    }
#pragma unroll
    for (int c = 0; c < 32; c++) s_h[c * 64 + lane] = h1h[c];
#pragma unroll 1
    for (int c = 0; c < 32; c++) {
        float hc = s_h[c * 64 + lane];
#pragma unroll
        for (int o = 0; o < 64; o++)
            h2[o] = __builtin_fmaf(w1[o * 64 + (32 + c)], hc, h2[o]);
    }
#pragma unroll
    for (int o = 0; o < 64; o++) h2[o] = fmaxf(h2[o], 0.0f);

#pragma unroll 2
    for (int o = 0; o < 128; o++) {
        const float* wr = w2 + o * 64;
        float acc = b2[o];
#pragma unroll
        for (int c = 0; c < 64; c++) acc = __builtin_fmaf(wr[c], h2[c], acc);
        acc = fmaxf(acc, 0.0f);
#pragma unroll
        for (int off = 32; off >= 1; off >>= 1)
            acc = fmaxf(acc, __shfl_down(acc, off));
        if (lane == 0) out1[((size_t)(b * 128 + o)) * S_TOT + sg] = acc;
    }
}

extern "C" void kernel_launch(void* const* d_in, const int* in_sizes, int n_in,
                              void* d_out, int out_size, void* d_ws, size_t ws_size,
                              hipStream_t stream) {
    const float* xyz  = (const float*)d_in[0];
    const float* pts  = (const float*)d_in[1];
    const float* attn = (const float*)d_in[2];
    const float* w0 = (const float*)d_in[3];
    const float* b0 = (const float*)d_in[4];
    const float* w1 = (const float*)d_in[5];
    const float* b1 = (const float*)d_in[6];
    const float* w2 = (const float*)d_in[7];
    const float* b2 = (const float*)d_in[8];

    float* out0 = (float*)d_out;                    // [B,3,S]
    float* out1 = out0 + (size_t)NB * 3 * S_TOT;    // [B,128,S]
    float* out2 = out1 + (size_t)NB * 128 * S_TOT;  // [B,1,S]

    // ws: wp (36 tiles * 1KB) | ptsTh bf16 [B][N][64] | cxyz | hdr
    unsigned short* wp    = (unsigned short*)d_ws;
    unsigned short* ptsTh = (unsigned short*)((char*)d_ws + 36864);
    float4*         cxyz  = (float4*)((char*)d_ws + 36864 + 8388608);
    int*            hdr   = (int*)((char*)cxyz + (size_t)16 * CCAP * 16);
    const size_t need = 36864 + 8388608 + (size_t)16 * CCAP * 16 + 128;

    if (ws_size >= need) {
        fps_compact<<<16, 1024, 0, stream>>>(xyz, attn, cxyz, hdr);
        fps_iter<<<16, 256, 0, stream>>>(attn, cxyz, hdr, out0, out2);
        fps_kernel<<<16, 1024, 0, stream>>>(xyz, attn, hdr, out0, out2);  // gated
        transpose_pts<<<dim3(NPTS / 64, NB), dim3(64, 4), 0, stream>>>(pts, ptsTh);
        pack_w<<<36, 64, 0, stream>>>(w0, w1, w2, wp);
        ball_mlp_mfma<<<NB * S_TOT, 64, 0, stream>>>(xyz, ptsTh, wp, b0, b1, b2,
                                                     out0, out1);
    } else {
        fps_kernel<<<16, 1024, 0, stream>>>(xyz, attn, nullptr, out0, out2);
        ball_mlp_fb<<<NB * S_TOT, 64, 0, stream>>>(xyz, pts, w0, b0, w1, b1,
                                                   w2, b2, out0, out1);
    }
}